// Round 10
// baseline (12239.232 us; speedup 1.0000x reference)
//
#include <hip/hip_runtime.h>
#include <hip/hip_bf16.h>

#define B_ 256
#define T_ 256
#define I_ 512
#define H_ 1024

typedef _Float16 half8 __attribute__((ext_vector_type(8)));
typedef float floatx4 __attribute__((ext_vector_type(4)));

__device__ __forceinline__ float fsig(float x) { return 1.f / (1.f + __expf(-x)); }
__device__ __forceinline__ float ftanh(float x) { return 1.f - 2.f / (__expf(2.f * x) + 1.f); }

// agent-scope write-through f16 store (visible cross-XCD at L3 without L2 flush)
__device__ __forceinline__ void st_h16(_Float16* p, _Float16 v) {
  unsigned short u = __builtin_bit_cast(unsigned short, v);
  __hip_atomic_store((unsigned short*)p, u, __ATOMIC_RELAXED, __HIP_MEMORY_SCOPE_AGENT);
}

// Permuted gate-row order: n' -> orig row g*H + h, g=(n'&63)>>4, h=(n'>>6)*16+(n'&15).
// Gate-tile n == gate g; unit j = 4*(lane>>4)+reg in the swapped D[gate][batch] layout.

__global__ __launch_bounds__(256) void prep_w(
    _Float16* __restrict__ dst, const float* __restrict__ src, int K) {
  const int np = blockIdx.y;
  const int k = blockIdx.x * 256 + threadIdx.x;
  const int cc = np & 63, g = cc >> 4, j = cc & 15;
  const int orig = g * H_ + (np >> 6) * 16 + j;
  dst[(size_t)np * K + k] = (_Float16)src[(size_t)orig * K + k];
}

__global__ __launch_bounds__(256) void prep_bias(
    float* __restrict__ bs0, float* __restrict__ bs1,
    const float* __restrict__ bih0, const float* __restrict__ bhh0,
    const float* __restrict__ bih1, const float* __restrict__ bhh1) {
  const int np = blockIdx.x * 256 + threadIdx.x;   // grid 16
  const int cc = np & 63, g = cc >> 4, j = cc & 15;
  const int orig = g * H_ + (np >> 6) * 16 + j;
  bs0[np] = bih0[orig] + bhh0[orig];
  bs1[np] = bih1[orig] + bhh1[orig];
}

struct MegaArgs {
  const float* ctx;
  const _Float16* W0p;  const _Float16* W1p;
  const _Float16* Wh0p; const _Float16* Wh1p;
  const float* bs0; const float* bs1;
  _Float16* h1ring; _Float16* h2ring;     // [2][B_*H_] cross-block
  _Float16* xgT0; _Float16* xgT1;         // [2][4096*256] gate-major, block-local
  float* hF;
  const float* init;
  unsigned* flags;                        // [256] progress flags
};

__device__ __forceinline__ void publish(unsigned* flags, int bid, unsigned v) {
  __syncthreads();   // drains all this block's stores before the flag
  if (threadIdx.x == 0) {
    asm volatile("" ::: "memory");
    __hip_atomic_store(&flags[bid], v, __ATOMIC_RELAXED, __HIP_MEMORY_SCOPE_AGENT);
  }
}

__device__ __forceinline__ void wait_strip(unsigned* flags, int strip, unsigned tgt) {
  if (threadIdx.x < 64) {
    unsigned* f0 = flags + strip * 64 + threadIdx.x;
    unsigned* f1 = flags + 128 + strip * 64 + threadIdx.x;
    for (;;) {
      const unsigned a = __hip_atomic_load(f0, __ATOMIC_RELAXED, __HIP_MEMORY_SCOPE_AGENT);
      const unsigned b = __hip_atomic_load(f1, __ATOMIC_RELAXED, __HIP_MEMORY_SCOPE_AGENT);
      if (__all(a >= tgt && b >= tgt)) break;
      __builtin_amdgcn_s_sleep(1);
    }
    __builtin_amdgcn_fence(__ATOMIC_ACQUIRE, "agent");   // invalidate stale L1/L2
  }
  __syncthreads();
}

// Persistent fused kernel: 256 blocks (1/CU). bid>>7=layer, (bid>>6)&1=strip, bid&63=colblock.
// Schedule: L0-rec t=s-1 (s:1..256); L0-gemm xg0[t=s] (s:0..255);
//           L1-gemm tau=s-2 (s:2..257); L1-rec t=s-3 (s:3..258). Rings depth 2.
__global__ __launch_bounds__(256, 1) void mega(MegaArgs a) {
  const int bid = blockIdx.x, tid = threadIdx.x;
  const int layer = bid >> 7, strip = (bid >> 6) & 1, nb = bid & 63;
  const int row0 = strip * 128;
  const int w = tid >> 6, lane = tid & 63, l15 = lane & 15, l4 = lane >> 4;

  __shared__ _Float16 whb[64 * 1024];   // 128 KB: resident W_hh slice (swizzled), A-operand
  __shared__ float red[32 * 128];       // 16 KB: reduce buffer (rotation-swizzled, 2 passes)

  // ---- init h rings (slot 1 = t=-1 state), write-through ----
  {
    const int idx = (bid * 256 + tid) * 4;
    const float4 v = *(const float4*)(a.init + idx);
    st_h16(a.h1ring + B_ * H_ + idx,     (_Float16)v.x);
    st_h16(a.h1ring + B_ * H_ + idx + 1, (_Float16)v.y);
    st_h16(a.h1ring + B_ * H_ + idx + 2, (_Float16)v.z);
    st_h16(a.h1ring + B_ * H_ + idx + 3, (_Float16)v.w);
    st_h16(a.h2ring + B_ * H_ + idx,     (_Float16)v.x);
    st_h16(a.h2ring + B_ * H_ + idx + 1, (_Float16)v.y);
    st_h16(a.h2ring + B_ * H_ + idx + 2, (_Float16)v.z);
    st_h16(a.h2ring + B_ * H_ + idx + 3, (_Float16)v.w);
  }

  // ---- stage resident W_hh slice -> LDS (swizzled granules) ----
  {
    const _Float16* Whp = (layer ? a.Wh1p : a.Wh0p) + (size_t)nb * 64 * 1024;
    const int row = tid & 63;
    const int gb = (tid >> 6) * 32;
    #pragma unroll
    for (int i = 0; i < 32; ++i) {
      const int g = gb + i;
      half8 v = *(const half8*)(Whp + (size_t)row * 1024 + g * 8);
      *(half8*)(whb + row * 1024 + ((g ^ (row & 7)) * 8)) = v;
    }
  }

  // ---- W_ih A-fragments, K-split by wave, persistent in VGPR ----
  const _Float16* Wg = layer ? a.W1p : a.W0p;
  const int gK = layer ? 1024 : 512;
  const int NC = layer ? 8 : 4;          // k-chunks of 32 per wave (gK/4/32)
  const int ksb = w * (gK >> 2);         // wave's k-slice base
  half8 bf[8][4];                        // [c][n]
  #pragma unroll
  for (int c = 0; c < 8; ++c)
    if (c < NC)
      #pragma unroll
      for (int n = 0; n < 4; ++n)
        bf[c][n] = *(const half8*)(Wg + (size_t)(nb * 64 + n * 16 + l15) * gK
                                   + ksb + c * 32 + l4 * 8);

  // bias for the two store passes (thread -> gate row tid>>3 within pass half)
  float bvp[2];
  bvp[0] = (layer ? a.bs1 : a.bs0)[nb * 64 + (tid >> 3)];
  bvp[1] = (layer ? a.bs1 : a.bs0)[nb * 64 + 32 + (tid >> 3)];

  float cst[8] = {0.f, 0.f, 0.f, 0.f, 0.f, 0.f, 0.f, 0.f};

  publish(a.flags, bid, 1u);

  for (int s = 0; s <= 258; ++s) {
    wait_strip(a.flags, strip, (unsigned)(s + 1));

    // ====== recurrent: D[64 gate][128 batch] = W_hh(LDS) x h^T, barrier-free ======
    const bool recAct = layer ? (s >= 3 && s <= 258) : (s >= 1 && s <= 256);
    if (recAct) {
      const _Float16* Asrc = (layer ? a.h2ring : a.h1ring) + (size_t)(s & 1) * (B_ * H_);
      const _Float16* xgr = (layer ? a.xgT1 : a.xgT0) + (size_t)((s - 1) & 1) * (4096 * 256);
      // B-frags: batch col = row0 + w*32 + m*16 + l15, k = c*32 + l4*8; depth-16 ring
      const _Float16* hb = Asrc + (size_t)(row0 + w * 32 + l15) * H_ + l4 * 8;
      const size_t hstep = (size_t)16 * H_;
      half8 rng[16][2];
      #pragma unroll
      for (int c = 0; c < 16; ++c) {
        rng[c][0] = *(const half8*)(hb + c * 32);
        rng[c][1] = *(const half8*)(hb + hstep + c * 32);
      }
      floatx4 racc[4][2] = {};   // [gate n][m]
      #pragma unroll
      for (int c = 0; c < 32; ++c) {
        half8 b0 = rng[c & 15][0];
        half8 b1 = rng[c & 15][1];
        if (c + 16 < 32) {
          rng[c & 15][0] = *(const half8*)(hb + (c + 16) * 32);
          rng[c & 15][1] = *(const half8*)(hb + hstep + (c + 16) * 32);
        }
        #pragma unroll
        for (int n = 0; n < 4; ++n) {
          const int wrow = n * 16 + l15;
          half8 wa = *(const half8*)(whb + wrow * 1024 + (((c * 4 + l4) ^ (wrow & 7)) * 8));
          racc[n][0] = __builtin_amdgcn_mfma_f32_16x16x32_f16(wa, b0, racc[n][0], 0, 0, 0);
          racc[n][1] = __builtin_amdgcn_mfma_f32_16x16x32_f16(wa, b1, racc[n][1], 0, 0, 0);
        }
      }
      // ---- register-local cell update: lane owns units j=4*l4+r, 2 batches ----
      const int t = layer ? (s - 3) : (s - 1);
      _Float16* hw = (layer ? a.h2ring : a.h1ring) + (size_t)((s - 1) & 1) * (B_ * H_);
      #pragma unroll
      for (int m = 0; m < 2; ++m) {
        const int batch = row0 + w * 32 + m * 16 + l15;
        #pragma unroll
        for (int r = 0; r < 4; ++r) {
          const int j = l4 * 4 + r;
          const size_t xb = (size_t)(nb * 64 + j) * 256 + batch;
          const float gi = racc[0][m][r] + (float)xgr[xb];
          const float gf = racc[1][m][r] + (float)xgr[xb + 16 * 256];
          const float gg = racc[2][m][r] + (float)xgr[xb + 32 * 256];
          const float go = racc[3][m][r] + (float)xgr[xb + 48 * 256];
          const float si = fsig(gi), sf = fsig(gf), so = fsig(go);
          const float tg = ftanh(gg);
          const float cn = sf * cst[m * 4 + r] + si * tg;
          const float hn = so * ftanh(cn);
          cst[m * 4 + r] = cn;
          st_h16(hw + (size_t)batch * H_ + nb * 16 + j, (_Float16)hn);
          if (layer == 1 && t == 255) a.hF[(size_t)batch * H_ + nb * 16 + j] = hn;
        }
      }
    }

    if (layer == 0) publish(a.flags, bid, (unsigned)(s + 2));  // h1[t=s-1] visible

    // ====== input GEMM: D[64 gate][128 batch], A=W_ih(VGPR, k-split), barrier-free ======
    const bool gAct = layer ? (s >= 2 && s <= 257) : (s <= 255);
    if (gAct) {
      floatx4 gacc[8][4] = {};   // [m][n]
      if (layer == 0) {
        const float* actb = a.ctx + (size_t)s * I_ + ksb + l4 * 8;
        half8 grng[2][8];
        auto ldc = [&](int c, int m) -> half8 {
          const float* p = actb + (size_t)(row0 + m * 16 + l15) * (T_ * I_) + c * 32;
          float4 f0 = *(const float4*)p;
          float4 f1 = *(const float4*)(p + 4);
          half8 h;
          h[0] = (_Float16)f0.x; h[1] = (_Float16)f0.y;
          h[2] = (_Float16)f0.z; h[3] = (_Float16)f0.w;
          h[4] = (_Float16)f1.x; h[5] = (_Float16)f1.y;
          h[6] = (_Float16)f1.z; h[7] = (_Float16)f1.w;
          return h;
        };
        #pragma unroll
        for (int m = 0; m < 8; ++m) grng[0][m] = ldc(0, m);
        #pragma unroll
        for (int m = 0; m < 8; ++m) grng[1][m] = ldc(1, m);
        #pragma unroll
        for (int c = 0; c < 4; ++c) {
          half8 bm[8];
          #pragma unroll
          for (int m = 0; m < 8; ++m) bm[m] = grng[c & 1][m];
          if (c + 2 < 4) {
            #pragma unroll
            for (int m = 0; m < 8; ++m) grng[c & 1][m] = ldc(c + 2, m);
          }
          #pragma unroll
          for (int m = 0; m < 8; ++m)
            #pragma unroll
            for (int n = 0; n < 4; ++n)
              gacc[m][n] = __builtin_amdgcn_mfma_f32_16x16x32_f16(bf[c][n], bm[m], gacc[m][n], 0, 0, 0);
        }
      } else {
        const _Float16* actb = a.h1ring + (size_t)(s & 1) * (B_ * H_) + ksb + l4 * 8;
        half8 grng[3][8];
        auto ldh = [&](int c, int m) -> half8 {
          return *(const half8*)(actb + (size_t)(row0 + m * 16 + l15) * H_ + c * 32);
        };
        #pragma unroll
        for (int c = 0; c < 3; ++c)
          #pragma unroll
          for (int m = 0; m < 8; ++m) grng[c][m] = ldh(c, m);
        #pragma unroll
        for (int c = 0; c < 8; ++c) {
          const int slot = c % 3;
          half8 bm[8];
          #pragma unroll
          for (int m = 0; m < 8; ++m) bm[m] = grng[slot][m];
          if (c + 3 < 8) {
            #pragma unroll
            for (int m = 0; m < 8; ++m) grng[slot][m] = ldh(c + 3, m);
          }
          #pragma unroll
          for (int m = 0; m < 8; ++m)
            #pragma unroll
            for (int n = 0; n < 4; ++n)
              gacc[m][n] = __builtin_amdgcn_mfma_f32_16x16x32_f16(bf[c][n], bm[m], gacc[m][n], 0, 0, 0);
        }
      }
      // ---- two-pass 4-wave sequential LDS reduce (gate halves), rotation swizzle ----
      // addr = g*128 + ((batch + 4g) & 127): injective per pass; write/add = 2 lanes/bank.
      _Float16* og = (layer ? a.xgT1 : a.xgT0) + (size_t)(s & 1) * (4096 * 256);
      #pragma unroll
      for (int p = 0; p < 2; ++p) {
        __syncthreads();
        if (w == 0) {
          #pragma unroll
          for (int m = 0; m < 8; ++m)
            #pragma unroll
            for (int nn = 0; nn < 2; ++nn)
              #pragma unroll
              for (int r = 0; r < 4; ++r) {
                const int g = nn * 16 + l4 * 4 + r;
                red[g * 128 + ((m * 16 + l15 + 4 * g) & 127)] = gacc[m][p * 2 + nn][r];
              }
        }
        __syncthreads();
        if (w == 1) {
          #pragma unroll
          for (int m = 0; m < 8; ++m)
            #pragma unroll
            for (int nn = 0; nn < 2; ++nn)
              #pragma unroll
              for (int r = 0; r < 4; ++r) {
                const int g = nn * 16 + l4 * 4 + r;
                red[g * 128 + ((m * 16 + l15 + 4 * g) & 127)] += gacc[m][p * 2 + nn][r];
              }
        }
        __syncthreads();
        if (w == 2) {
          #pragma unroll
          for (int m = 0; m < 8; ++m)
            #pragma unroll
            for (int nn = 0; nn < 2; ++nn)
              #pragma unroll
              for (int r = 0; r < 4; ++r) {
                const int g = nn * 16 + l4 * 4 + r;
                red[g * 128 + ((m * 16 + l15 + 4 * g) & 127)] += gacc[m][p * 2 + nn][r];
              }
        }
        __syncthreads();
        if (w == 3) {
          #pragma unroll
          for (int m = 0; m < 8; ++m)
            #pragma unroll
            for (int nn = 0; nn < 2; ++nn)
              #pragma unroll
              for (int r = 0; r < 4; ++r) {
                const int g = nn * 16 + l4 * 4 + r;
                red[g * 128 + ((m * 16 + l15 + 4 * g) & 127)] += gacc[m][p * 2 + nn][r];
              }
        }
        __syncthreads();
        // store: thread -> gate row gr2 = tid>>3 (0..31), batches (tid&7)*16..+16
        const int gr2 = tid >> 3;
        const int bq = (tid & 7) * 16;
        const float bv = bvp[p];
        half8 h0, h1v;
        #pragma unroll
        for (int e = 0; e < 8; ++e)
          h0[e] = (_Float16)(red[gr2 * 128 + ((bq + e + 4 * gr2) & 127)] + bv);
        #pragma unroll
        for (int e = 0; e < 8; ++e)
          h1v[e] = (_Float16)(red[gr2 * 128 + ((bq + 8 + e + 4 * gr2) & 127)] + bv);
        *(half8*)(og + (size_t)(nb * 64 + p * 32 + gr2) * 256 + row0 + bq) = h0;
        *(half8*)(og + (size_t)(nb * 64 + p * 32 + gr2) * 256 + row0 + bq + 8) = h1v;
      }
    }

    if (layer == 1) publish(a.flags, bid, (unsigned)(s + 2));
  }
}

__global__ __launch_bounds__(256) void readout(
    const float* __restrict__ hF, const float* __restrict__ Wro,
    const float* __restrict__ bro, float* __restrict__ out) {
  const int b = blockIdx.x;
  const int tid = threadIdx.x;
  float p = 0.f;
  for (int h = tid; h < H_; h += 256) p += hF[(size_t)b * H_ + h] * Wro[h];
  #pragma unroll
  for (int off = 32; off; off >>= 1) p += __shfl_down(p, off, 64);
  __shared__ float redr[4];
  if ((tid & 63) == 0) redr[tid >> 6] = p;
  __syncthreads();
  if (tid == 0) out[b] = redr[0] + redr[1] + redr[2] + redr[3] + bro[0];
}

extern "C" void kernel_launch(void* const* d_in, const int* in_sizes, int n_in,
                              void* d_out, int out_size, void* d_ws, size_t ws_size,
                              hipStream_t stream) {
  const float* init_hidden = (const float*)d_in[0];
  const float* ctx   = (const float*)d_in[1];
  const float* W_ih0 = (const float*)d_in[2];
  const float* W_hh0 = (const float*)d_in[3];
  const float* b_ih0 = (const float*)d_in[4];
  const float* b_hh0 = (const float*)d_in[5];
  const float* W_ih1 = (const float*)d_in[6];
  const float* W_hh1 = (const float*)d_in[7];
  const float* b_ih1 = (const float*)d_in[8];
  const float* b_hh1 = (const float*)d_in[9];
  const float* W_ro  = (const float*)d_in[10];
  const float* b_ro  = (const float*)d_in[11];

  char* ws = (char*)d_ws;
  const size_t MB = 1 << 20;
  _Float16* W0p    = (_Float16*)(ws);                      // 4 MiB
  _Float16* Wh0p   = (_Float16*)(ws + 4 * MB);             // 8 MiB
  _Float16* W1p    = (_Float16*)(ws + 12 * MB);            // 8 MiB
  _Float16* Wh1p   = (_Float16*)(ws + 20 * MB);            // 8 MiB
  float*    bs0    = (float*)(ws + 28 * MB);               // 16 KiB
  float*    bs1    = (float*)(ws + 28 * MB + 16384);       // 16 KiB
  float*    hF     = (float*)(ws + 28 * MB + 32768);       // 1 MiB
  _Float16* h1ring = (_Float16*)(ws + 29 * MB + 32768);    // 1 MiB (2 slots)
  _Float16* h2ring = (_Float16*)(ws + 30 * MB + 32768);    // 1 MiB
  _Float16* xgT0   = (_Float16*)(ws + 31 * MB + 32768);    // 4 MiB (2 slots)
  _Float16* xgT1   = (_Float16*)(ws + 35 * MB + 32768);    // 4 MiB
  unsigned* flags  = (unsigned*)(ws + 39 * MB + 32768);    // 1 KiB

  hipMemsetAsync(flags, 0, 4096, stream);
  prep_w<<<dim3(2, 4096), 256, 0, stream>>>(W0p, W_ih0, 512);
  prep_w<<<dim3(4, 4096), 256, 0, stream>>>(Wh0p, W_hh0, 1024);
  prep_w<<<dim3(4, 4096), 256, 0, stream>>>(W1p, W_ih1, 1024);
  prep_w<<<dim3(4, 4096), 256, 0, stream>>>(Wh1p, W_hh1, 1024);
  prep_bias<<<dim3(16), 256, 0, stream>>>(bs0, bs1, b_ih0, b_hh0, b_ih1, b_hh1);

  MegaArgs ma;
  ma.ctx = ctx; ma.W0p = W0p; ma.W1p = W1p; ma.Wh0p = Wh0p; ma.Wh1p = Wh1p;
  ma.bs0 = bs0; ma.bs1 = bs1; ma.h1ring = h1ring; ma.h2ring = h2ring;
  ma.xgT0 = xgT0; ma.xgT1 = xgT1; ma.hF = hF; ma.init = init_hidden;
  ma.flags = flags;
  mega<<<dim3(256), dim3(256), 0, stream>>>(ma);

  readout<<<dim3(256), 256, 0, stream>>>(hF, W_ro, b_ro, (float*)d_out);
}